// Round 1
// baseline (156.288 us; speedup 1.0000x reference)
//
#include <hip/hip_runtime.h>
#include <math.h>

// Problem constants (from reference): B=8, planes=4, Cin=64, Cout=128, H=W=64, K=3,S=1,D=1,P=1
#define CIN   64
#define COUT  128
#define WIMG  64
#define HW    4096
#define EPSF  1e-6f
#define LOG_EPS -13.815510557964274f   // logf(1e-6)

// ---------------- prep: w1n = wnorm(w1x,w1y) [576], w2n = wnorm(w2x,w2y) [8192] into ws ----------------
__global__ void prep_weights(const float* __restrict__ w1x, const float* __restrict__ w1y,
                             const float* __restrict__ w2x, const float* __restrict__ w2y,
                             float* __restrict__ wsn) {
  __shared__ float red[256];
  const int tid = threadIdx.x;
  float s1 = 0.f, s2 = 0.f;
  for (int i = tid; i < 576; i += 256)  { float v = w1x[i] + w1y[i]; s1 += v * v; }
  for (int i = tid; i < 8192; i += 256) { float v = w2x[i] + w2y[i]; s2 += v * v; }
  red[tid] = s1; __syncthreads();
  for (int s = 128; s > 0; s >>= 1) { if (tid < s) red[tid] += red[tid + s]; __syncthreads(); }
  const float t1 = red[0]; __syncthreads();
  red[tid] = s2; __syncthreads();
  for (int s = 128; s > 0; s >>= 1) { if (tid < s) red[tid] += red[tid + s]; __syncthreads(); }
  const float t2 = red[0];
  const float r1 = 1.0f / t1, r2 = 1.0f / t2;
  for (int i = tid; i < 576; i += 256)  { float v = w1x[i] + w1y[i]; wsn[i]       = v * v * r1; }
  for (int i = tid; i < 8192; i += 256) { float v = w2x[i] + w2y[i]; wsn[576 + i] = v * v * r2; }
}

// ---------------- fused depthwise(3x3) + pointwise(1x1) conv, plane-specialized ----------------
// grid: 512 blocks = (b*4+plane) [32] x row-tile [16, 4 rows each]; block: 512 threads.
// LDS ~53 KB -> with <=128 VGPR (launch_bounds 512,4) we get 2 blocks/CU: whole grid co-resident.
#define BLK 512
__global__ __launch_bounds__(BLK, 4) void fused_conv(
    const float* __restrict__ x,
    const float* __restrict__ w1x, const float* __restrict__ w1y,
    const float* __restrict__ w2x, const float* __restrict__ w2y,
    const float* __restrict__ wsn,   // [0..575]=w1n, [576..8767]=w2n
    float* __restrict__ out) {
  const int tid   = threadIdx.x;
  const int rt    = blockIdx.x & 15;   // row tile: rows rt*4 .. rt*4+3
  const int bp    = blockIdx.x >> 4;   // b*4 + plane
  const int plane = bp & 3;
  const bool is_abs = (plane == 1);
  const float* w1 = (plane < 2) ? wsn         : (plane == 2 ? w1x : w1y);
  const float* w2 = (plane < 2) ? (wsn + 576) : (plane == 2 ? w2x : w2y);

  // LDS: all rows 16B-aligned
  __shared__ float xs[16][6][68];   // input chunk tile: 16 ch x (4+2 halo rows) x (64+2 halo cols), cols padded to 68
  __shared__ float ts[16][260];     // depthwise result: 16 ch x 256 px (+4 pad)
  __shared__ float w2s[16][132];    // w2 chunk transposed: [c within chunk][o], padded
  __shared__ float w1s[576];        // full selected w1

  for (int i = tid; i < 576; i += BLK) w1s[i] = w1[i];

  // phase-C mapping: wave og owns outputs o0..o0+15; lane owns 4 consecutive pixels
  const int og  = tid >> 6;          // 0..7 (= wave id)
  const int o0  = og * 16;
  const int p0c = (tid & 63) * 4;    // 0..252

  float acc[64];
  #pragma unroll
  for (int j = 0; j < 64; ++j) acc[j] = 0.f;

  const float* xbase = x + (size_t)bp * CIN * HW;

  for (int cc = 0; cc < 4; ++cc) {   // channel chunks of 16
    // ---- phase A: stage input tile (with halo + padding) and w2 chunk ----
    for (int i = tid; i < 16 * 6 * 66; i += BLK) {
      int c   = i / 396;
      int rem = i - c * 396;
      int r   = rem / 66;
      int u   = rem - r * 66;
      int gr  = rt * 4 + r - 1;      // image row
      int gc  = u - 1;               // image col
      float v;
      if ((unsigned)gr < 64u && (unsigned)gc < 64u) {
        v = xbase[(size_t)(cc * 16 + c) * HW + gr * WIMG + gc];
        if (is_abs) v = logf(v + EPSF);
      } else {
        v = is_abs ? LOG_EPS : 0.f;  // zero-pad; log-domain pad = log(0+eps)
      }
      xs[c][r][u] = v;
    }
    for (int i = tid; i < 2048; i += BLK) {
      int o = i >> 4;
      int c = i & 15;
      w2s[c][o] = w2[o * CIN + cc * 16 + c];
    }
    __syncthreads();

    // ---- phase B: depthwise 3x3 -> ts. 32 threads per channel, 8 px per thread ----
    {
      const int c    = tid >> 5;          // 0..15
      const int p0   = (tid & 31) * 8;    // 0..248
      const int ri   = p0 >> 6;           // tile row 0..3
      const int col0 = p0 & 63;           // multiple of 8
      float wv[9];
      #pragma unroll
      for (int k = 0; k < 9; ++k) wv[k] = w1s[(cc * 16 + c) * 9 + k];
      float at[8];
      #pragma unroll
      for (int pp = 0; pp < 8; ++pp) at[pp] = 0.f;
      #pragma unroll
      for (int kr = 0; kr < 3; ++kr) {
        const float* xr = &xs[c][ri + kr][col0];
        float4 a0 = *(const float4*)xr;
        float4 a1 = *(const float4*)(xr + 4);
        float2 a2 = *(const float2*)(xr + 8);
        float xv[10] = {a0.x, a0.y, a0.z, a0.w, a1.x, a1.y, a1.z, a1.w, a2.x, a2.y};
        #pragma unroll
        for (int pp = 0; pp < 8; ++pp) {
          at[pp] += xv[pp]     * wv[kr * 3 + 0];
          at[pp] += xv[pp + 1] * wv[kr * 3 + 1];
          at[pp] += xv[pp + 2] * wv[kr * 3 + 2];
        }
      }
      *(float4*)&ts[c][p0]     = make_float4(at[0], at[1], at[2], at[3]);
      *(float4*)&ts[c][p0 + 4] = make_float4(at[4], at[5], at[6], at[7]);
    }
    __syncthreads();

    // ---- phase C: pointwise GEMM accumulate (16 c-steps) ----
    #pragma unroll
    for (int k = 0; k < 16; ++k) {
      float4 tq  = *(const float4*)&ts[k][p0c];
      float4 wq0 = *(const float4*)&w2s[k][o0];       // broadcast (whole wave same o0)
      float4 wq1 = *(const float4*)&w2s[k][o0 + 4];
      float4 wq2 = *(const float4*)&w2s[k][o0 + 8];
      float4 wq3 = *(const float4*)&w2s[k][o0 + 12];
      const float wvals[16] = {wq0.x, wq0.y, wq0.z, wq0.w, wq1.x, wq1.y, wq1.z, wq1.w,
                               wq2.x, wq2.y, wq2.z, wq2.w, wq3.x, wq3.y, wq3.z, wq3.w};
      #pragma unroll
      for (int jj = 0; jj < 16; ++jj) {
        const float w = wvals[jj];
        acc[jj * 4 + 0] += w * tq.x;
        acc[jj * 4 + 1] += w * tq.y;
        acc[jj * 4 + 2] += w * tq.z;
        acc[jj * 4 + 3] += w * tq.w;
      }
    }
    __syncthreads();  // protect ts/w2s/xs before next chunk overwrites
  }

  // ---- epilogue: (optional exp) + float4 stores ----
  float* obase = out + (size_t)bp * COUT * HW + rt * 256 + p0c;
  #pragma unroll
  for (int jj = 0; jj < 16; ++jj) {
    float4 v = make_float4(acc[jj * 4 + 0], acc[jj * 4 + 1], acc[jj * 4 + 2], acc[jj * 4 + 3]);
    if (is_abs) { v.x = expf(v.x); v.y = expf(v.y); v.z = expf(v.z); v.w = expf(v.w); }
    *(float4*)(obase + (size_t)(o0 + jj) * HW) = v;
  }
}

extern "C" void kernel_launch(void* const* d_in, const int* in_sizes, int n_in,
                              void* d_out, int out_size, void* d_ws, size_t ws_size,
                              hipStream_t stream) {
  const float* x   = (const float*)d_in[0];
  const float* w1x = (const float*)d_in[1];
  const float* w1y = (const float*)d_in[2];
  const float* w2x = (const float*)d_in[3];
  const float* w2y = (const float*)d_in[4];
  float* out = (float*)d_out;
  float* wsn = (float*)d_ws;   // needs 8768 floats = 35 KB

  prep_weights<<<1, 256, 0, stream>>>(w1x, w1y, w2x, w2y, wsn);
  fused_conv<<<512, BLK, 0, stream>>>(x, w1x, w1y, w2x, w2y, wsn, out);
}